// Round 9
// baseline (2370.909 us; speedup 1.0000x reference)
//
#include <hip/hip_runtime.h>
#include <hip/hip_bf16.h>

// KWSNet: conv1d+relu -> 2x GRU (fwd-scan, two weight sets) -> sliding mean -> linear(2)
// B=64, M=80, T=2000, C=H=256, K=5; Tc=1996, W=96, Tout=1901, out (1901,1,64,2) fp32.
//
// R21: R20's fat kernel (scan_k || proj_{k+1} || conv_{k+2}) WORKED (2475->2366)
// but fat dispatches ran 145us vs scan-alone 93us. Not data contention (proj adds
// ~4% L2 volume); it's CU CO-RESIDENCY: VGPR=152/LDS=36864 -> 3 blocks/CU, so
// proj blocks (MFMA bursts + 774K LDS bank conflicts) stack onto scan CUs and
// stretch the scan's latency-critical step chain (Occupancy 9.3 = ~12 waves/CU).
// Fix: smem -> 86016B (>80KB) => 1 block/CU chip-wide (R12 precedent: 96KB
// static LDS compiles/launches). Scan gets 128 exclusive CUs (R12 rate, 93us);
// proj/conv run 128-at-a-time on the other 128 CUs (~40us total, hidden).
// Everything else byte-identical to R20 for clean A/B.
// Predict: fat 145 -> 95-110us (tail ~80), LDS_Block ~86K, Occ ~3-4%,
// total 2366 -> ~1700-1850us. Falsify: fat >=130 => co-residency not the
// mechanism -> next lever proj write-coalescing.

#define TT    2000
#define TC    1996
#define NB    64
#define MCH   80
#define NN    1536           // 2 * 3H
#define TOUT  1901
#define TCH   126            // chunk length (last chunk = 106)
#define NCHK  16
#define CROWS (TCH * NB)     // 8064 rows per chunk parity

typedef _Float16 h8_t __attribute__((ext_vector_type(8)));
typedef float    f4_t __attribute__((ext_vector_type(4)));

#define WQSCALE 254.0f
#define INV8    (1.0f / (254.0f * 127.0f))

// ---------------- workspace layout (bytes), total ~61.6 MB (proven ws >= 76.5 MB) ----------------
#define OFF_SEQC ((size_t)0)            // fp16 [2 parity][8064][256]      = 8,257,536
#define OFF_XG   ((size_t)8257536)      // fp16 [2 parity][2 dir][8064][768] = 49,545,216
#define OFF_WT   ((size_t)57802752)     // fp32 [400][256]                 = 409,600
#define OFF_WCAT ((size_t)58212352)     // fp16 [1536][256]                = 786,432
#define OFF_HST  ((size_t)58998784)     // fp32 [128][256]                 = 131,072
#define OFF_WQ   ((size_t)59129856)     // u32  [2][3][256][64]            = 393,216
#define OFF_PS2  ((size_t)59523072)     // fp32 [2][TC][64][2]             = 2,043,904 -> 61,566,976

// ---------------- prep: transpose conv_w, fp16 w_ih concat, int8-quantize W_hh ----------------
__global__ void prep_kernel(const float* __restrict__ conv_w,
                            const float* __restrict__ wihf,
                            const float* __restrict__ wihr,
                            const float* __restrict__ whhf,
                            const float* __restrict__ whhr,
                            float* __restrict__ wT,
                            _Float16* __restrict__ wcat,
                            unsigned* __restrict__ wq) {
    int idx = blockIdx.x * 256 + threadIdx.x;
    if (idx < 400 * 256) {
        int c = idx & 255, mk = idx >> 8;
        wT[idx] = conv_w[c * 400 + mk];
    }
    int i2 = idx - 400 * 256;
    if (i2 >= 0 && i2 < NN * 256) {
        int k = i2 & 255, n = i2 >> 8;
        float v = (n < 768) ? wihf[n * 256 + k] : wihr[(n - 768) * 256 + k];
        wcat[i2] = (_Float16)v;
    }
    int i4 = idx - (400 * 256 + NN * 256);
    if (i4 >= 0 && i4 < 2 * 3 * 256 * 64) {
        int r  = i4 & 255;
        int j  = (i4 >> 8) & 63;
        int dg = i4 >> 14;               // 0..5 = d*3+g
        const float* whh = (dg >= 3) ? whhr : whhf;
        int g = (dg >= 3) ? dg - 3 : dg;
        const float* wp = whh + (size_t)(g * 256 + r) * 256 + 4 * j;
        unsigned v = 0;
#pragma unroll
        for (int kk = 0; kk < 4; ++kk) {
            float q = rintf(wp[kk] * WQSCALE);
            q = fminf(fmaxf(q, -127.f), 127.f);
            v |= ((unsigned)((int)q & 0xFF)) << (8 * kk);
        }
        wq[((size_t)dg * 256 + r) * 64 + j] = v;
    }
}

// ---------------- fat kernel: scan_k || proj_{k+1} || conv_{k+2} ----------------
#define SD4(a, b, c) __builtin_amdgcn_sdot4((int)(a), (int)(b), (c), false)

__global__ __launch_bounds__(256)
void fat_kernel(
    // scan role (nscan blocks)
    int nscan, const _Float16* __restrict__ xg_s, const uint4* __restrict__ wq,
    const float* __restrict__ bhhf, const float* __restrict__ bhhr,
    const float* __restrict__ clfw, float* __restrict__ hstate,
    float* __restrict__ psum2, int t0s, int lens, int first,
    // proj role (nproj blocks)
    int nproj, const _Float16* __restrict__ seqc_p, const _Float16* __restrict__ wcat,
    const float* __restrict__ bihf, const float* __restrict__ bihr,
    _Float16* __restrict__ xg_p,
    // conv role (nconv blocks)
    int nconv, const float* __restrict__ x, const float* __restrict__ wT,
    const float* __restrict__ conv_b, _Float16* __restrict__ seqc_c,
    int t0c, int lenc)
{
    // 84 KB static LDS: forces 1 block/CU (role exclusivity). Only the first
    // 36864 B are used (proj As+Bs = max role demand); the rest is occupancy pad.
    __shared__ __align__(16) char smem[86016];
    int bid = blockIdx.x;
    int tid = threadIdx.x;

    if (bid < nscan) {
        // ======== persistent GRU scan chunk (R12 inner loop + fused clf) ========
        int d = bid >> 6, b = bid & 63;
        int i = tid, lane = tid & 63, wv = tid >> 6;
        const float* bhh = d ? bhhr : bhhf;
        unsigned (*hq8)[64]  = (unsigned(*)[64])smem;       // [2][64] int8 h dbuf
        float (*cwp)[4][2]   = (float(*)[4][2])(smem + 512); // [2][4][2] clf partials

        // int8 weights, rows {i, i+256, i+512}: UNPINNED (R12 behavior: compiler
        // streams from L2 at ~108 B/cyc/CU -- the proven-best delivery tier)
        uint4 wa[16], wb[16], wc[16];
        {
            const uint4* pa = wq + ((size_t)(d * 3 + 0) * 256 + i) * 16;
            const uint4* pb = wq + ((size_t)(d * 3 + 1) * 256 + i) * 16;
            const uint4* pc = wq + ((size_t)(d * 3 + 2) * 256 + i) * 16;
#pragma unroll
            for (int k = 0; k < 16; ++k) { wa[k] = pa[k]; wb[k] = pb[k]; wc[k] = pc[k]; }
        }
        float bhr = bhh[i], bhz = bhh[256 + i], bhn = bhh[512 + i];
        float cw0 = clfw[d * 256 + i], cw1 = clfw[512 + d * 256 + i];
        float h = first ? 0.f : hstate[(size_t)bid * 256 + i];

        ((char*)&hq8[0][0])[i] = (char)(int)rintf(h * 127.f);
        __syncthreads();

        const _Float16* xgp = xg_s + (size_t)d * CROWS * 768 + (size_t)b * 768 + i;
        float xr = (float)xgp[0], xz = (float)xgp[256], xn = (float)xgp[512];
        xgp += (size_t)64 * 768;

        int cur = 0;
        for (int t = 0; t < lens; ++t) {
            // prefetch next step's xg (last iter reads past chunk -> inside ws, unused)
            float pxr = (float)xgp[0], pxz = (float)xgp[256], pxn = (float)xgp[512];
            xgp += (size_t)64 * 768;

            const uint4* hqp = (const uint4*)&hq8[cur][0];   // 16 b128 broadcasts
            int i0 = 0, i1 = 0, i2 = 0;
#pragma unroll
            for (int k = 0; k < 16; ++k) {
                uint4 hv = hqp[k];
                i0 = SD4(wa[k].x, hv.x, i0); i0 = SD4(wa[k].y, hv.y, i0);
                i0 = SD4(wa[k].z, hv.z, i0); i0 = SD4(wa[k].w, hv.w, i0);
                i1 = SD4(wb[k].x, hv.x, i1); i1 = SD4(wb[k].y, hv.y, i1);
                i1 = SD4(wb[k].z, hv.z, i1); i1 = SD4(wb[k].w, hv.w, i1);
                i2 = SD4(wc[k].x, hv.x, i2); i2 = SD4(wc[k].y, hv.y, i2);
                i2 = SD4(wc[k].z, hv.z, i2); i2 = SD4(wc[k].w, hv.w, i2);
            }

            float hr = (float)i0 * INV8 + bhr;
            float hz = (float)i1 * INV8 + bhz;
            float hn = (float)i2 * INV8 + bhn;
            float rg = 1.f / (1.f + __expf(-(xr + hr)));
            float zg = 1.f / (1.f + __expf(-(xz + hz)));
            float xnr = xn + rg * hn;
            float nv = 1.f - 2.f / (__expf(2.f * xnr) + 1.f);   // tanh
            h = (1.f - zg) * nv + zg * h;

            // fused clf partial: butterfly within wave, partials via LDS
            float s0 = cw0 * h, s1 = cw1 * h;
#pragma unroll
            for (int off = 32; off; off >>= 1) {
                s0 += __shfl_xor(s0, off, 64);
                s1 += __shfl_xor(s1, off, 64);
            }
            int nxt = cur ^ 1;
            ((char*)&hq8[nxt][0])[i] = (char)(int)rintf(h * 127.f);
            if (lane == 0) { cwp[nxt][wv][0] = s0; cwp[nxt][wv][1] = s1; }
            __syncthreads();
            if (i == 0) {
                float a0 = cwp[nxt][0][0] + cwp[nxt][1][0] + cwp[nxt][2][0] + cwp[nxt][3][0];
                float a1 = cwp[nxt][0][1] + cwp[nxt][1][1] + cwp[nxt][2][1] + cwp[nxt][3][1];
                float* pp = psum2 + (((size_t)d * TC + (t0s + t)) * 64 + b) * 2;
                pp[0] = a0; pp[1] = a1;
            }
            cur = nxt;
            xr = pxr; xz = pxz; xn = pxn;
        }
        hstate[(size_t)bid * 256 + i] = h;

    } else if (bid < nscan + nproj) {
        // ======== proj: xg[d][row][j] = seqc @ w_ih^T + b_ih (fp16 MFMA) ========
        int pb = bid - nscan;
        int row0 = (pb / 12) * 128;
        int n0   = (pb % 12) * 128;
        _Float16 (*As)[72] = (_Float16(*)[72])smem;
        _Float16 (*Bs)[72] = (_Float16(*)[72])(smem + 18432);
        int lane = tid & 63, wv = tid >> 6;
        int wr = wv >> 1, wcn = wv & 1;                // 2x2 waves of 64x64
        int fm = lane & 15, fq = lane >> 4;
        f4_t acc[4][4];
#pragma unroll
        for (int mt = 0; mt < 4; ++mt)
#pragma unroll
            for (int nt = 0; nt < 4; ++nt) acc[mt][nt] = (f4_t){0.f, 0.f, 0.f, 0.f};

        int r = tid >> 1, part = tid & 1;
        for (int kc = 0; kc < 4; ++kc) {
            const uint4* srcA = (const uint4*)&seqc_p[(size_t)(row0 + r) * 256 + kc * 64 + part * 32];
            const uint4* srcB = (const uint4*)&wcat[(size_t)(n0 + r) * 256 + kc * 64 + part * 32];
            uint4* dstA = (uint4*)&As[r][part * 32];
            uint4* dstB = (uint4*)&Bs[r][part * 32];
            dstA[0] = srcA[0]; dstA[1] = srcA[1]; dstA[2] = srcA[2]; dstA[3] = srcA[3];
            dstB[0] = srcB[0]; dstB[1] = srcB[1]; dstB[2] = srcB[2]; dstB[3] = srcB[3];
            __syncthreads();
#pragma unroll
            for (int ks = 0; ks < 64; ks += 32) {
                h8_t af[4], bf[4];
#pragma unroll
                for (int mt = 0; mt < 4; ++mt)
                    af[mt] = *(const h8_t*)&As[wr * 64 + mt * 16 + fm][ks + fq * 8];
#pragma unroll
                for (int nt = 0; nt < 4; ++nt)
                    bf[nt] = *(const h8_t*)&Bs[wcn * 64 + nt * 16 + fm][ks + fq * 8];
#pragma unroll
                for (int mt = 0; mt < 4; ++mt)
#pragma unroll
                    for (int nt = 0; nt < 4; ++nt)
                        acc[mt][nt] = __builtin_amdgcn_mfma_f32_16x16x32_f16(
                            af[mt], bf[nt], acc[mt][nt], 0, 0, 0);
            }
            __syncthreads();
        }
#pragma unroll
        for (int nt = 0; nt < 4; ++nt) {
            int col = n0 + wcn * 64 + nt * 16 + fm;
            int d = (col < 768) ? 0 : 1;
            int j = col - d * 768;
            float bias = d ? bihr[j] : bihf[j];
            size_t obase = (size_t)d * CROWS * 768 + j;
#pragma unroll
            for (int mt = 0; mt < 4; ++mt) {
                int row = row0 + wr * 64 + mt * 16 + fq * 4;
#pragma unroll
                for (int rr = 0; rr < 4; ++rr)
                    xg_p[obase + (size_t)(row + rr) * 768] = (_Float16)(acc[mt][nt][rr] + bias);
            }
        }

    } else {
        // ======== conv1d(valid,K=5)+bias+relu -> seqc_c ========
        int cb = bid - nscan - nproj;
        int tile = cb >> 6;              // 0..1 (covers 128 t >= TCH)
        int b    = cb & 63;
        float (*xs)[68] = (float(*)[68])smem;
        for (int idx = tid; idx < MCH * 68; idx += 256) {
            int m = idx / 68, ii = idx - m * 68;
            int tt = t0c + tile * 64 + ii;
            xs[m][ii] = (tt < TT) ? x[(size_t)b * (MCH * TT) + m * TT + tt] : 0.f;
        }
        __syncthreads();
        int lane = tid & 63, tg = tid >> 6;
        float acc[4][16];
#pragma unroll
        for (int cq = 0; cq < 4; ++cq)
#pragma unroll
            for (int t = 0; t < 16; ++t) acc[cq][t] = 0.f;

        for (int m = 0; m < MCH; ++m) {
            float xr_[20];
#pragma unroll
            for (int q = 0; q < 5; ++q) {
                float4 v = *(const float4*)&xs[m][tg * 16 + q * 4];
                xr_[q * 4 + 0] = v.x; xr_[q * 4 + 1] = v.y;
                xr_[q * 4 + 2] = v.z; xr_[q * 4 + 3] = v.w;
            }
#pragma unroll
            for (int cq = 0; cq < 4; ++cq) {
                int c = lane + cq * 64;
                const float* wp = wT + (size_t)(m * 5) * 256 + c;
                float w0_ = wp[0], w1_ = wp[256], w2_ = wp[512], w3_ = wp[768], w4_ = wp[1024];
#pragma unroll
                for (int t = 0; t < 16; ++t)
                    acc[cq][t] += w0_ * xr_[t] + w1_ * xr_[t + 1] + w2_ * xr_[t + 2]
                                + w3_ * xr_[t + 3] + w4_ * xr_[t + 4];
            }
        }
#pragma unroll
        for (int cq = 0; cq < 4; ++cq) {
            int c = lane + cq * 64;
            float cb_ = conv_b[c];
            for (int t = 0; t < 16; ++t) {
                int tl = tile * 64 + tg * 16 + t;
                if (tl < lenc) {
                    float v = acc[cq][t] + cb_;
                    v = v > 0.f ? v : 0.f;
                    seqc_c[((size_t)tl * 64 + b) * 256 + c] = (_Float16)v;
                }
            }
        }
    }
}

// ---------------- final: sliding mean over W steps (both dirs) + clf bias ----------------
__global__ void final_kernel(const float* __restrict__ psum2, const float* __restrict__ clf_b,
                             const int* __restrict__ win, float* __restrict__ out) {
    int idx = blockIdx.x * 256 + threadIdx.x;
    if (idx >= TOUT * 128) return;
    int c = idx & 1;
    int rem = idx >> 1;
    int b = rem & 63;
    int tau = rem >> 6;
    int W = win[0] - 5 + 1;   // 96
    const float* p0 = psum2;
    const float* p1 = psum2 + (size_t)TC * 64 * 2;
    float s = 0.f;
    for (int j = 0; j < W; ++j) {
        size_t o = ((size_t)(tau + j) * 64 + b) * 2 + c;
        s += p0[o] + p1[o];
    }
    out[idx] = s / (float)W + clf_b[c];
}

extern "C" void kernel_launch(void* const* d_in, const int* in_sizes, int n_in,
                              void* d_out, int out_size, void* d_ws, size_t ws_size,
                              hipStream_t stream) {
    const float* x      = (const float*)d_in[0];
    const float* conv_w = (const float*)d_in[1];
    const float* conv_b = (const float*)d_in[2];
    const float* w_ih_f = (const float*)d_in[3];
    const float* w_hh_f = (const float*)d_in[4];
    const float* b_ih_f = (const float*)d_in[5];
    const float* b_hh_f = (const float*)d_in[6];
    const float* w_ih_r = (const float*)d_in[7];
    const float* w_hh_r = (const float*)d_in[8];
    const float* b_ih_r = (const float*)d_in[9];
    const float* b_hh_r = (const float*)d_in[10];
    const float* clf_w  = (const float*)d_in[11];
    const float* clf_b  = (const float*)d_in[12];
    const int*   win    = (const int*)d_in[13];
    float* out = (float*)d_out;

    char* ws = (char*)d_ws;
    _Float16* seqc = (_Float16*)(ws + OFF_SEQC);
    _Float16* xg   = (_Float16*)(ws + OFF_XG);
    float*    wT   = (float*)(ws + OFF_WT);
    _Float16* wcat = (_Float16*)(ws + OFF_WCAT);
    float*    hst  = (float*)(ws + OFF_HST);
    const uint4* wqp = (const uint4*)(ws + OFF_WQ);
    unsigned* wq   = (unsigned*)(ws + OFF_WQ);
    float*    ps2  = (float*)(ws + OFF_PS2);

    const size_t XGP = (size_t)2 * CROWS * 768;   // xg elements per parity
    const size_t SQP = (size_t)CROWS * 256;       // seqc elements per parity

    int prep_elems = 400 * 256 + NN * 256 + 2 * 3 * 256 * 64;
    prep_kernel<<<(prep_elems + 255) / 256, 256, 0, stream>>>(
        conv_w, w_ih_f, w_ih_r, w_hh_f, w_hh_r, wT, wcat, wq);

    auto lenk = [](int k) { return (k < NCHK - 1) ? TCH : (TC - (NCHK - 1) * TCH); }; // 126 / 106

    // prologue A: conv_0 -> seqc[p0]
    fat_kernel<<<128, 256, 0, stream>>>(
        0, xg, wqp, b_hh_f, b_hh_r, clf_w, hst, ps2, 0, 0, 0,
        0, seqc, wcat, b_ih_f, b_ih_r, xg,
        128, x, wT, conv_b, seqc, 0, lenk(0));

    // prologue B: proj_0 (seqc[p0] -> xg[p0]) || conv_1 -> seqc[p1]
    fat_kernel<<<(lenk(0) / 2) * 12 + 128, 256, 0, stream>>>(
        0, xg, wqp, b_hh_f, b_hh_r, clf_w, hst, ps2, 0, 0, 0,
        (lenk(0) / 2) * 12, seqc, wcat, b_ih_f, b_ih_r, xg,
        128, x, wT, conv_b, seqc + SQP, TCH, lenk(1));

    // main loop: launch k = scan_k || proj_{k+1} || conv_{k+2}
    for (int k = 0; k < NCHK; ++k) {
        int lens = lenk(k);
        int np = (k + 1 < NCHK) ? (lenk(k + 1) / 2) * 12 : 0;
        int nc = (k + 2 < NCHK) ? 128 : 0;
        fat_kernel<<<128 + np + nc, 256, 0, stream>>>(
            128, xg + (size_t)(k & 1) * XGP, wqp, b_hh_f, b_hh_r, clf_w, hst, ps2,
            k * TCH, lens, (k == 0) ? 1 : 0,
            np, seqc + (size_t)((k + 1) & 1) * SQP, wcat, b_ih_f, b_ih_r,
            xg + (size_t)((k + 1) & 1) * XGP,
            nc, x, wT, conv_b, seqc + (size_t)(k & 1) * SQP,
            (k + 2) * TCH, (k + 2 < NCHK) ? lenk(k + 2) : 0);
    }

    final_kernel<<<(TOUT * 128 + 255) / 256, 256, 0, stream>>>(ps2, clf_b, win, out);
}

// Round 11
// 2357.167 us; speedup vs baseline: 1.0058x; 1.0058x over previous
//
#include <hip/hip_runtime.h>
#include <hip/hip_bf16.h>

// KWSNet: conv1d+relu -> 2x GRU (fwd-scan, two weight sets) -> sliding mean -> linear(2)
// B=64, M=80, T=2000, C=H=256, K=5; Tc=1996, W=96, Tout=1901, out (1901,1,64,2) fp32.
//
// R23 == R22 with Bs-staging bug fixed. R22 NaN'd: persistent proj staged only
// 8 uint4 (64 halfs) per (r,part) but each owns 128 halfs -> half of Bs
// uninitialized -> NaN. Fix: 16 uint4. Design rationale unchanged:
// R21 proved placement irrelevant (1 blk/CU == 3 blk/CU == 145us) -> bottleneck
// is aggregate L2 BW (scan alone = 34 TB/s = ceiling). Proj's wcat re-reads
// (756 x 786KB = 594MB) are the marginal traffic. Persistent proj: 108 blocks
// (12 n-tiles x NRG=9 row-groups), Bs (128-col wcat slice, all K) staged ONCE,
// loop ~7 row-tiles. wcat traffic -> 6.6MB.
// Predict: fat 145 -> 100-115us, total -> ~1850-2000us, absmax ~0.0078.
// Falsify: fat >=135us => L2-traffic theory wrong -> isolate w/ scan-only fat.

#define TT    2000
#define TC    1996
#define NB    64
#define MCH   80
#define NN    1536           // 2 * 3H
#define TOUT  1901
#define TCH   126            // chunk length (last chunk = 106)
#define NCHK  16
#define NRG   9              // proj row-groups: nproj = 12*NRG = 108 blocks
#define CROWS (TCH * NB)     // 8064 rows per chunk parity

typedef _Float16 h8_t __attribute__((ext_vector_type(8)));
typedef float    f4_t __attribute__((ext_vector_type(4)));

#define WQSCALE 254.0f
#define INV8    (1.0f / (254.0f * 127.0f))

// ---------------- workspace layout (bytes), total ~61.6 MB (proven ws >= 76.5 MB) ----------------
#define OFF_SEQC ((size_t)0)            // fp16 [2 parity][8064][256]      = 8,257,536
#define OFF_XG   ((size_t)8257536)      // fp16 [2 parity][2 dir][8064][768] = 49,545,216
#define OFF_WT   ((size_t)57802752)     // fp32 [400][256]                 = 409,600
#define OFF_WCAT ((size_t)58212352)     // fp16 [1536][256]                = 786,432
#define OFF_HST  ((size_t)58998784)     // fp32 [128][256]                 = 131,072
#define OFF_WQ   ((size_t)59129856)     // u32  [2][3][256][64]            = 393,216
#define OFF_PS2  ((size_t)59523072)     // fp32 [2][TC][64][2]             = 2,043,904 -> 61,566,976

// ---------------- prep: transpose conv_w, fp16 w_ih concat, int8-quantize W_hh ----------------
__global__ void prep_kernel(const float* __restrict__ conv_w,
                            const float* __restrict__ wihf,
                            const float* __restrict__ wihr,
                            const float* __restrict__ whhf,
                            const float* __restrict__ whhr,
                            float* __restrict__ wT,
                            _Float16* __restrict__ wcat,
                            unsigned* __restrict__ wq) {
    int idx = blockIdx.x * 256 + threadIdx.x;
    if (idx < 400 * 256) {
        int c = idx & 255, mk = idx >> 8;
        wT[idx] = conv_w[c * 400 + mk];
    }
    int i2 = idx - 400 * 256;
    if (i2 >= 0 && i2 < NN * 256) {
        int k = i2 & 255, n = i2 >> 8;
        float v = (n < 768) ? wihf[n * 256 + k] : wihr[(n - 768) * 256 + k];
        wcat[i2] = (_Float16)v;
    }
    int i4 = idx - (400 * 256 + NN * 256);
    if (i4 >= 0 && i4 < 2 * 3 * 256 * 64) {
        int r  = i4 & 255;
        int j  = (i4 >> 8) & 63;
        int dg = i4 >> 14;               // 0..5 = d*3+g
        const float* whh = (dg >= 3) ? whhr : whhf;
        int g = (dg >= 3) ? dg - 3 : dg;
        const float* wp = whh + (size_t)(g * 256 + r) * 256 + 4 * j;
        unsigned v = 0;
#pragma unroll
        for (int kk = 0; kk < 4; ++kk) {
            float q = rintf(wp[kk] * WQSCALE);
            q = fminf(fmaxf(q, -127.f), 127.f);
            v |= ((unsigned)((int)q & 0xFF)) << (8 * kk);
        }
        wq[((size_t)dg * 256 + r) * 64 + j] = v;
    }
}

// ---------------- fat kernel: scan_k || proj_{k+1} || conv_{k+2} ----------------
#define SD4(a, b, c) __builtin_amdgcn_sdot4((int)(a), (int)(b), (c), false)

__global__ __launch_bounds__(256)
void fat_kernel(
    // scan role (nscan blocks)
    int nscan, const _Float16* __restrict__ xg_s, const uint4* __restrict__ wq,
    const float* __restrict__ bhhf, const float* __restrict__ bhhr,
    const float* __restrict__ clfw, float* __restrict__ hstate,
    float* __restrict__ psum2, int t0s, int lens, int first,
    // proj role (nproj blocks, persistent: loop row-tiles with Bs staged once)
    int nproj, const _Float16* __restrict__ seqc_p, const _Float16* __restrict__ wcat,
    const float* __restrict__ bihf, const float* __restrict__ bihr,
    _Float16* __restrict__ xg_p, int lenp,
    // conv role (nconv blocks)
    int nconv, const float* __restrict__ x, const float* __restrict__ wT,
    const float* __restrict__ conv_b, _Float16* __restrict__ seqc_c,
    int t0c, int lenc)
{
    // 86016 B static LDS (same as R21): Bs_full 67584 + As 18432.
    __shared__ __align__(16) char smem[86016];
    int bid = blockIdx.x;
    int tid = threadIdx.x;

    if (bid < nscan) {
        // ======== persistent GRU scan chunk (R12 inner loop + fused clf) ========
        int d = bid >> 6, b = bid & 63;
        int i = tid, lane = tid & 63, wv = tid >> 6;
        const float* bhh = d ? bhhr : bhhf;
        unsigned (*hq8)[64]  = (unsigned(*)[64])smem;       // [2][64] int8 h dbuf
        float (*cwp)[4][2]   = (float(*)[4][2])(smem + 512); // [2][4][2] clf partials

        // int8 weights, rows {i, i+256, i+512}: UNPINNED (R12 behavior: compiler
        // streams from L2 at ~108 B/cyc/CU -- the proven-best delivery tier)
        uint4 wa[16], wb[16], wc[16];
        {
            const uint4* pa = wq + ((size_t)(d * 3 + 0) * 256 + i) * 16;
            const uint4* pb = wq + ((size_t)(d * 3 + 1) * 256 + i) * 16;
            const uint4* pc = wq + ((size_t)(d * 3 + 2) * 256 + i) * 16;
#pragma unroll
            for (int k = 0; k < 16; ++k) { wa[k] = pa[k]; wb[k] = pb[k]; wc[k] = pc[k]; }
        }
        float bhr = bhh[i], bhz = bhh[256 + i], bhn = bhh[512 + i];
        float cw0 = clfw[d * 256 + i], cw1 = clfw[512 + d * 256 + i];
        float h = first ? 0.f : hstate[(size_t)bid * 256 + i];

        ((char*)&hq8[0][0])[i] = (char)(int)rintf(h * 127.f);
        __syncthreads();

        const _Float16* xgp = xg_s + (size_t)d * CROWS * 768 + (size_t)b * 768 + i;
        float xr = (float)xgp[0], xz = (float)xgp[256], xn = (float)xgp[512];
        xgp += (size_t)64 * 768;

        int cur = 0;
        for (int t = 0; t < lens; ++t) {
            // prefetch next step's xg (last iter reads past chunk -> inside ws, unused)
            float pxr = (float)xgp[0], pxz = (float)xgp[256], pxn = (float)xgp[512];
            xgp += (size_t)64 * 768;

            const uint4* hqp = (const uint4*)&hq8[cur][0];   // 16 b128 broadcasts
            int i0 = 0, i1 = 0, i2 = 0;
#pragma unroll
            for (int k = 0; k < 16; ++k) {
                uint4 hv = hqp[k];
                i0 = SD4(wa[k].x, hv.x, i0); i0 = SD4(wa[k].y, hv.y, i0);
                i0 = SD4(wa[k].z, hv.z, i0); i0 = SD4(wa[k].w, hv.w, i0);
                i1 = SD4(wb[k].x, hv.x, i1); i1 = SD4(wb[k].y, hv.y, i1);
                i1 = SD4(wb[k].z, hv.z, i1); i1 = SD4(wb[k].w, hv.w, i1);
                i2 = SD4(wc[k].x, hv.x, i2); i2 = SD4(wc[k].y, hv.y, i2);
                i2 = SD4(wc[k].z, hv.z, i2); i2 = SD4(wc[k].w, hv.w, i2);
            }

            float hr = (float)i0 * INV8 + bhr;
            float hz = (float)i1 * INV8 + bhz;
            float hn = (float)i2 * INV8 + bhn;
            float rg = 1.f / (1.f + __expf(-(xr + hr)));
            float zg = 1.f / (1.f + __expf(-(xz + hz)));
            float xnr = xn + rg * hn;
            float nv = 1.f - 2.f / (__expf(2.f * xnr) + 1.f);   // tanh
            h = (1.f - zg) * nv + zg * h;

            // fused clf partial: butterfly within wave, partials via LDS
            float s0 = cw0 * h, s1 = cw1 * h;
#pragma unroll
            for (int off = 32; off; off >>= 1) {
                s0 += __shfl_xor(s0, off, 64);
                s1 += __shfl_xor(s1, off, 64);
            }
            int nxt = cur ^ 1;
            ((char*)&hq8[nxt][0])[i] = (char)(int)rintf(h * 127.f);
            if (lane == 0) { cwp[nxt][wv][0] = s0; cwp[nxt][wv][1] = s1; }
            __syncthreads();
            if (i == 0) {
                float a0 = cwp[nxt][0][0] + cwp[nxt][1][0] + cwp[nxt][2][0] + cwp[nxt][3][0];
                float a1 = cwp[nxt][0][1] + cwp[nxt][1][1] + cwp[nxt][2][1] + cwp[nxt][3][1];
                float* pp = psum2 + (((size_t)d * TC + (t0s + t)) * 64 + b) * 2;
                pp[0] = a0; pp[1] = a1;
            }
            cur = nxt;
            xr = pxr; xz = pxz; xn = pxn;
        }
        hstate[(size_t)bid * 256 + i] = h;

    } else if (bid < nscan + nproj) {
        // ======== proj (persistent): xg = seqc @ w_ih^T + b_ih (fp16 MFMA) ========
        // block = (n0 tile, row-group rg); Bs (128-col wcat slice, all K) staged
        // ONCE; loop row-tiles tIdx = rg, rg+NRG, ... -> wcat traffic /7.
        int pb = bid - nscan;
        int n0 = (pb % 12) * 128;
        int rg = pb / 12;                       // 0..NRG-1
        int ntiles = lenp >> 1;                 // (lenp*64)/128 row tiles
        _Float16 (*Bs)[264] = (_Float16(*)[264])smem;            // 67584 B
        _Float16 (*As)[72]  = (_Float16(*)[72])(smem + 67584);   // 18432 B
        int lane = tid & 63, wv = tid >> 6;
        int wr = wv >> 1, wcn = wv & 1;                // 2x2 waves of 64x64
        int fm = lane & 15, fq = lane >> 4;
        int r = tid >> 1, part = tid & 1;

        // stage Bs once: rows n0+r, this thread's 128-half slice (16 uint4).
        // (R22 bug: only 8 uint4 staged -> half of Bs uninitialized -> NaN.)
        {
            const uint4* srcB = (const uint4*)&wcat[(size_t)(n0 + r) * 256 + part * 128];
            uint4* dstB = (uint4*)&Bs[r][part * 128];
#pragma unroll
            for (int q = 0; q < 16; ++q) dstB[q] = srcB[q];
        }

        for (int tIdx = rg; tIdx < ntiles; tIdx += NRG) {
            int row0 = tIdx * 128;
            f4_t acc[4][4];
#pragma unroll
            for (int mt = 0; mt < 4; ++mt)
#pragma unroll
                for (int nt = 0; nt < 4; ++nt) acc[mt][nt] = (f4_t){0.f, 0.f, 0.f, 0.f};

            for (int kc = 0; kc < 4; ++kc) {
                const uint4* srcA = (const uint4*)&seqc_p[(size_t)(row0 + r) * 256 + kc * 64 + part * 32];
                uint4* dstA = (uint4*)&As[r][part * 32];
                dstA[0] = srcA[0]; dstA[1] = srcA[1]; dstA[2] = srcA[2]; dstA[3] = srcA[3];
                __syncthreads();
#pragma unroll
                for (int ks = 0; ks < 64; ks += 32) {
                    h8_t af[4], bf[4];
#pragma unroll
                    for (int mt = 0; mt < 4; ++mt)
                        af[mt] = *(const h8_t*)&As[wr * 64 + mt * 16 + fm][ks + fq * 8];
#pragma unroll
                    for (int nt = 0; nt < 4; ++nt)
                        bf[nt] = *(const h8_t*)&Bs[wcn * 64 + nt * 16 + fm][kc * 64 + ks + fq * 8];
#pragma unroll
                    for (int mt = 0; mt < 4; ++mt)
#pragma unroll
                        for (int nt = 0; nt < 4; ++nt)
                            acc[mt][nt] = __builtin_amdgcn_mfma_f32_16x16x32_f16(
                                af[mt], bf[nt], acc[mt][nt], 0, 0, 0);
                }
                __syncthreads();
            }
#pragma unroll
            for (int nt = 0; nt < 4; ++nt) {
                int col = n0 + wcn * 64 + nt * 16 + fm;
                int d = (col < 768) ? 0 : 1;
                int j = col - d * 768;
                float bias = d ? bihr[j] : bihf[j];
                size_t obase = (size_t)d * CROWS * 768 + j;
#pragma unroll
                for (int mt = 0; mt < 4; ++mt) {
                    int row = row0 + wr * 64 + mt * 16 + fq * 4;
#pragma unroll
                    for (int rr = 0; rr < 4; ++rr)
                        xg_p[obase + (size_t)(row + rr) * 768] = (_Float16)(acc[mt][nt][rr] + bias);
                }
            }
        }

    } else {
        // ======== conv1d(valid,K=5)+bias+relu -> seqc_c ========
        int cb = bid - nscan - nproj;
        int tile = cb >> 6;              // 0..1 (covers 128 t >= TCH)
        int b    = cb & 63;
        float (*xs)[68] = (float(*)[68])smem;
        for (int idx = tid; idx < MCH * 68; idx += 256) {
            int m = idx / 68, ii = idx - m * 68;
            int tt = t0c + tile * 64 + ii;
            xs[m][ii] = (tt < TT) ? x[(size_t)b * (MCH * TT) + m * TT + tt] : 0.f;
        }
        __syncthreads();
        int lane = tid & 63, tg = tid >> 6;
        float acc[4][16];
#pragma unroll
        for (int cq = 0; cq < 4; ++cq)
#pragma unroll
            for (int t = 0; t < 16; ++t) acc[cq][t] = 0.f;

        for (int m = 0; m < MCH; ++m) {
            float xr_[20];
#pragma unroll
            for (int q = 0; q < 5; ++q) {
                float4 v = *(const float4*)&xs[m][tg * 16 + q * 4];
                xr_[q * 4 + 0] = v.x; xr_[q * 4 + 1] = v.y;
                xr_[q * 4 + 2] = v.z; xr_[q * 4 + 3] = v.w;
            }
#pragma unroll
            for (int cq = 0; cq < 4; ++cq) {
                int c = lane + cq * 64;
                const float* wp = wT + (size_t)(m * 5) * 256 + c;
                float w0_ = wp[0], w1_ = wp[256], w2_ = wp[512], w3_ = wp[768], w4_ = wp[1024];
#pragma unroll
                for (int t = 0; t < 16; ++t)
                    acc[cq][t] += w0_ * xr_[t] + w1_ * xr_[t + 1] + w2_ * xr_[t + 2]
                                + w3_ * xr_[t + 3] + w4_ * xr_[t + 4];
            }
        }
#pragma unroll
        for (int cq = 0; cq < 4; ++cq) {
            int c = lane + cq * 64;
            float cb_ = conv_b[c];
            for (int t = 0; t < 16; ++t) {
                int tl = tile * 64 + tg * 16 + t;
                if (tl < lenc) {
                    float v = acc[cq][t] + cb_;
                    v = v > 0.f ? v : 0.f;
                    seqc_c[((size_t)tl * 64 + b) * 256 + c] = (_Float16)v;
                }
            }
        }
    }
}

// ---------------- final: sliding mean over W steps (both dirs) + clf bias ----------------
__global__ void final_kernel(const float* __restrict__ psum2, const float* __restrict__ clf_b,
                             const int* __restrict__ win, float* __restrict__ out) {
    int idx = blockIdx.x * 256 + threadIdx.x;
    if (idx >= TOUT * 128) return;
    int c = idx & 1;
    int rem = idx >> 1;
    int b = rem & 63;
    int tau = rem >> 6;
    int W = win[0] - 5 + 1;   // 96
    const float* p0 = psum2;
    const float* p1 = psum2 + (size_t)TC * 64 * 2;
    float s = 0.f;
    for (int j = 0; j < W; ++j) {
        size_t o = ((size_t)(tau + j) * 64 + b) * 2 + c;
        s += p0[o] + p1[o];
    }
    out[idx] = s / (float)W + clf_b[c];
}

extern "C" void kernel_launch(void* const* d_in, const int* in_sizes, int n_in,
                              void* d_out, int out_size, void* d_ws, size_t ws_size,
                              hipStream_t stream) {
    const float* x      = (const float*)d_in[0];
    const float* conv_w = (const float*)d_in[1];
    const float* conv_b = (const float*)d_in[2];
    const float* w_ih_f = (const float*)d_in[3];
    const float* w_hh_f = (const float*)d_in[4];
    const float* b_ih_f = (const float*)d_in[5];
    const float* b_hh_f = (const float*)d_in[6];
    const float* w_ih_r = (const float*)d_in[7];
    const float* w_hh_r = (const float*)d_in[8];
    const float* b_ih_r = (const float*)d_in[9];
    const float* b_hh_r = (const float*)d_in[10];
    const float* clf_w  = (const float*)d_in[11];
    const float* clf_b  = (const float*)d_in[12];
    const int*   win    = (const int*)d_in[13];
    float* out = (float*)d_out;

    char* ws = (char*)d_ws;
    _Float16* seqc = (_Float16*)(ws + OFF_SEQC);
    _Float16* xg   = (_Float16*)(ws + OFF_XG);
    float*    wT   = (float*)(ws + OFF_WT);
    _Float16* wcat = (_Float16*)(ws + OFF_WCAT);
    float*    hst  = (float*)(ws + OFF_HST);
    const uint4* wqp = (const uint4*)(ws + OFF_WQ);
    unsigned* wq   = (unsigned*)(ws + OFF_WQ);
    float*    ps2  = (float*)(ws + OFF_PS2);

    const size_t XGP = (size_t)2 * CROWS * 768;   // xg elements per parity
    const size_t SQP = (size_t)CROWS * 256;       // seqc elements per parity

    int prep_elems = 400 * 256 + NN * 256 + 2 * 3 * 256 * 64;
    prep_kernel<<<(prep_elems + 255) / 256, 256, 0, stream>>>(
        conv_w, w_ih_f, w_ih_r, w_hh_f, w_hh_r, wT, wcat, wq);

    auto lenk = [](int k) { return (k < NCHK - 1) ? TCH : (TC - (NCHK - 1) * TCH); }; // 126 / 106

    // prologue A: conv_0 -> seqc[p0]
    fat_kernel<<<128, 256, 0, stream>>>(
        0, xg, wqp, b_hh_f, b_hh_r, clf_w, hst, ps2, 0, 0, 0,
        0, seqc, wcat, b_ih_f, b_ih_r, xg, 0,
        128, x, wT, conv_b, seqc, 0, lenk(0));

    // prologue B: proj_0 (seqc[p0] -> xg[p0]) || conv_1 -> seqc[p1]
    fat_kernel<<<12 * NRG + 128, 256, 0, stream>>>(
        0, xg, wqp, b_hh_f, b_hh_r, clf_w, hst, ps2, 0, 0, 0,
        12 * NRG, seqc, wcat, b_ih_f, b_ih_r, xg, lenk(0),
        128, x, wT, conv_b, seqc + SQP, TCH, lenk(1));

    // main loop: launch k = scan_k || proj_{k+1} || conv_{k+2}
    for (int k = 0; k < NCHK; ++k) {
        int lens = lenk(k);
        int np = (k + 1 < NCHK) ? 12 * NRG : 0;
        int lp = (k + 1 < NCHK) ? lenk(k + 1) : 0;
        int nc = (k + 2 < NCHK) ? 128 : 0;
        fat_kernel<<<128 + np + nc, 256, 0, stream>>>(
            128, xg + (size_t)(k & 1) * XGP, wqp, b_hh_f, b_hh_r, clf_w, hst, ps2,
            k * TCH, lens, (k == 0) ? 1 : 0,
            np, seqc + (size_t)((k + 1) & 1) * SQP, wcat, b_ih_f, b_ih_r,
            xg + (size_t)((k + 1) & 1) * XGP, lp,
            nc, x, wT, conv_b, seqc + (size_t)(k & 1) * SQP,
            (k + 2) * TCH, (k + 2 < NCHK) ? lenk(k + 2) : 0);
    }

    final_kernel<<<(TOUT * 128 + 255) / 256, 256, 0, stream>>>(ps2, clf_b, win, out);
}